// Round 4
// baseline (331.743 us; speedup 1.0000x reference)
//
#include <hip/hip_runtime.h>
#include <math.h>

#define CB 512
#define CS 1024
#define CT 50
#define PF 4   // x-prefetch depth / renorm cadence

typedef float v2f __attribute__((ext_vector_type(2)));

__global__ void zero_out_kernel(float* out) { out[0] = 0.0f; }

// Compiler-level fence only — same-wave DS ops complete in order on CDNA,
// we just stop the compiler/scheduler from reordering. No waitcnt drain.
__device__ __forceinline__ void wave_fence() {
    __builtin_amdgcn_wave_barrier();
    asm volatile("" ::: "memory");
}

__device__ __forceinline__ int lane0_bits(float v) {
    return __builtin_amdgcn_readlane(__float_as_int(v), 0);
}

__global__ __launch_bounds__(64) void crf_scan_kernel(
    const float* __restrict__ scores,    // (B,S,T)
    const int*   __restrict__ tags,      // (B,S)
    const int*   __restrict__ mask,      // (B,S)
    const float* __restrict__ trans,     // (T,T)
    const float* __restrict__ start_tr,  // (T)
    const float* __restrict__ end_tr,    // (T)
    float* __restrict__ out)             // scalar
{
    const int b    = blockIdx.x;
    const int lane = threadIdx.x;
    const int xl   = (lane < CT) ? lane : 0;

    __shared__ __attribute__((aligned(16))) float sTrans[CT * CT];
    __shared__ __attribute__((aligned(16))) float sPF[64];
    __shared__ __attribute__((aligned(16))) float sPR[64];

    for (int k = lane; k < CT * CT; k += 64) sTrans[k] = trans[k];
    __syncthreads();

    // Fwd chain needs E column `lane`; bwd chain needs E row `lane`.
    // Packed pairs for v_pk_fma_f32.
    v2f evF[CT / 2], evR[CT / 2];
    #pragma unroll
    for (int i = 0; i < CT; i += 2) {
        evF[i / 2] = (v2f){ __expf(sTrans[(i    ) * CT + xl]),
                            __expf(sTrans[(i + 1) * CT + xl]) };
        evR[i / 2] = (v2f){ __expf(sTrans[xl * CT + i    ]),
                            __expf(sTrans[xl * CT + i + 1]) };
    }

    // sequence length (prefix mask)
    const int* mrow = mask + (size_t)b * CS;
    int len = 0;
    for (int t = lane; t < CS; t += 64) len += mrow[t];
    #pragma unroll
    for (int off = 32; off; off >>= 1) len += __shfl_xor(len, off);

    const float* srow = scores + (size_t)b * CS * CT;
    const float* sx   = srow + xl;

    const int tm     = (len - 1) >> 1;                    // split point
    const int countF = tm;                                // fwd steps t=1..tm
    const int countB = (len >= 2) ? (len - 2 - tm) : 0;   // bwd -> C_{tm+1}
    const int npair  = (countB < countF) ? countB : countF;   // countF-npair <= 1

    // linear-domain states
    float stF = __expf(start_tr[xl] + sx[0]);
    float stR = (len >= 2) ? __expf(end_tr[xl] + sx[(size_t)(len - 1) * CT])
                           : __expf(end_tr[xl]);
    int kexpF = 0, kexpR = 0;

    // one paired step: both chains write, both dot, both scale — interleaved ILP
    #define STEP2(EXF, EXR)                                                 \
    {                                                                       \
        sPF[lane] = stF; sPR[lane] = stR;                                   \
        wave_fence();                                                       \
        v2f aF0 = {0.f,0.f}, aF1 = {0.f,0.f};                               \
        v2f aR0 = {0.f,0.f}, aR1 = {0.f,0.f};                               \
        _Pragma("unroll")                                                   \
        for (int i = 0; i < 48; i += 4) {                                   \
            const float4 pf = *(const float4*)&sPF[i];                      \
            const float4 pr = *(const float4*)&sPR[i];                      \
            aF0 = __builtin_elementwise_fma((v2f){pf.x, pf.y}, evF[i/2    ], aF0); \
            aR0 = __builtin_elementwise_fma((v2f){pr.x, pr.y}, evR[i/2    ], aR0); \
            aF1 = __builtin_elementwise_fma((v2f){pf.z, pf.w}, evF[i/2 + 1], aF1); \
            aR1 = __builtin_elementwise_fma((v2f){pr.z, pr.w}, evR[i/2 + 1], aR1); \
        }                                                                   \
        {                                                                   \
            const v2f pf = *(const v2f*)&sPF[48];                           \
            const v2f pr = *(const v2f*)&sPR[48];                           \
            aF0 = __builtin_elementwise_fma(pf, evF[24], aF0);              \
            aR0 = __builtin_elementwise_fma(pr, evR[24], aR0);              \
        }                                                                   \
        wave_fence();                                                       \
        stF = ((aF0.x + aF0.y) + (aF1.x + aF1.y)) * (EXF);                  \
        stR = ((aR0.x + aR0.y) + (aR1.x + aR1.y)) * (EXR);                  \
    }

    // single-chain steps for remainders (reuse the paired body shape)
    #define STEPF(EXF)                                                      \
    {                                                                       \
        sPF[lane] = stF;                                                    \
        wave_fence();                                                       \
        v2f aF0 = {0.f,0.f}, aF1 = {0.f,0.f};                               \
        _Pragma("unroll")                                                   \
        for (int i = 0; i < 48; i += 4) {                                   \
            const float4 pf = *(const float4*)&sPF[i];                      \
            aF0 = __builtin_elementwise_fma((v2f){pf.x, pf.y}, evF[i/2    ], aF0); \
            aF1 = __builtin_elementwise_fma((v2f){pf.z, pf.w}, evF[i/2 + 1], aF1); \
        }                                                                   \
        { const v2f pf = *(const v2f*)&sPF[48];                             \
          aF0 = __builtin_elementwise_fma(pf, evF[24], aF0); }              \
        wave_fence();                                                       \
        stF = ((aF0.x + aF0.y) + (aF1.x + aF1.y)) * (EXF);                  \
    }
    #define STEPR(EXR)                                                      \
    {                                                                       \
        sPR[lane] = stR;                                                    \
        wave_fence();                                                       \
        v2f aR0 = {0.f,0.f}, aR1 = {0.f,0.f};                               \
        _Pragma("unroll")                                                   \
        for (int i = 0; i < 48; i += 4) {                                   \
            const float4 pr = *(const float4*)&sPR[i];                      \
            aR0 = __builtin_elementwise_fma((v2f){pr.x, pr.y}, evR[i/2    ], aR0); \
            aR1 = __builtin_elementwise_fma((v2f){pr.z, pr.w}, evR[i/2 + 1], aR1); \
        }                                                                   \
        { const v2f pr = *(const v2f*)&sPR[48];                             \
          aR0 = __builtin_elementwise_fma(pr, evR[24], aR0); }              \
        wave_fence();                                                       \
        stR = ((aR0.x + aR0.y) + (aR1.x + aR1.y)) * (EXR);                  \
    }

    // renorm each chain by the power-of-2 part of its lane-0 value
    #define RENORM(ST, KE)                                                  \
    {                                                                       \
        int sb = lane0_bits(ST);                                            \
        int e  = (sb >> 23) & 0xff;                                         \
        KE    += e - 127;                                                   \
        ST    *= __int_as_float((254 - e) << 23);                           \
    }

    // ---- paired scan: 4-step chunks, dual 4-deep x prefetch ----
    float xpf[PF], xpr[PF];
    #pragma unroll
    for (int k = 0; k < PF; ++k) {
        int iF = 1 + k;                                  // < CS always
        int iR = (len - 2) - k; if (iR < 0) iR = 0;
        xpf[k] = sx[(size_t)iF * CT];
        xpr[k] = sx[(size_t)iR * CT];
    }
    int k = 0;
    while (k + PF <= npair) {
        float exF[PF], exR[PF];
        #pragma unroll
        for (int j = 0; j < PF; ++j) { exF[j] = __expf(xpf[j]); exR[j] = __expf(xpr[j]); }
        #pragma unroll
        for (int j = 0; j < PF; ++j) {
            int iF = 1 + (k + PF + j);
            int iR = (len - 2) - (k + PF + j); if (iR < 0) iR = 0;
            xpf[j] = sx[(size_t)iF * CT];
            xpr[j] = sx[(size_t)iR * CT];
        }
        RENORM(stF, kexpF); RENORM(stR, kexpR);
        STEP2(exF[0], exR[0]); STEP2(exF[1], exR[1]);
        STEP2(exF[2], exR[2]); STEP2(exF[3], exR[3]);
        k += PF;
    }
    {
        int r = 0;
        for (; k < npair; ++k, ++r) {
            float eF = __expf(xpf[r]), eR = __expf(xpr[r]);
            RENORM(stF, kexpF); RENORM(stR, kexpR);
            STEP2(eF, eR);
        }
        // fwd may have one extra step (countF = npair or npair+1)
        if (countF > npair) {
            float eF = __expf((r < PF) ? xpf[r] : sx[(size_t)(1 + npair) * CT]);
            RENORM(stF, kexpF);
            STEPF(eF);
        }
    }
    // bwd epilogue: B_tm = E * C_{tm+1} (no exp(x) factor)
    if (len >= 2) { RENORM(stR, kexpR); STEPR(1.0f) }
    RENORM(stF, kexpF); RENORM(stR, kexpR);
    #undef STEP2
    #undef STEPF
    #undef STEPR
    #undef RENORM

    // ---- combine: den = log sum_i aF[i]*B[i] + (kexpF+kexpR)*ln2 ----
    float vp = (lane < CT) ? stF * stR : 0.0f;
    #pragma unroll
    for (int off = 32; off; off >>= 1) vp += __shfl_xor(vp, off);
    float den = (float)(kexpF + kexpR) * 0.6931471805599453f + __logf(vp);

    // ---- numerator: gold-path score ----
    const int* trow = tags + (size_t)b * CS;
    float nsum = 0.0f;
    for (int t = lane; t < CS; t += 64) {
        if (t < len) {
            int tg = trow[t];
            nsum += srow[(size_t)t * CT + tg];
            if (t >= 1) nsum += sTrans[trow[t - 1] * CT + tg];
        }
    }
    #pragma unroll
    for (int off = 32; off; off >>= 1) nsum += __shfl_xor(nsum, off);

    if (lane == 0) {
        nsum += start_tr[trow[0]] + end_tr[trow[len - 1]];
        atomicAdd(out, (den - nsum) * (1.0f / CB));
    }
}

extern "C" void kernel_launch(void* const* d_in, const int* in_sizes, int n_in,
                              void* d_out, int out_size, void* d_ws, size_t ws_size,
                              hipStream_t stream) {
    const float* scores   = (const float*)d_in[0];
    const int*   tags     = (const int*)d_in[1];
    const int*   mask     = (const int*)d_in[2];
    const float* trans    = (const float*)d_in[3];
    const float* start_tr = (const float*)d_in[4];
    const float* end_tr   = (const float*)d_in[5];
    float* out = (float*)d_out;

    zero_out_kernel<<<1, 1, 0, stream>>>(out);
    crf_scan_kernel<<<CB, 64, 0, stream>>>(scores, tags, mask, trans,
                                           start_tr, end_tr, out);
}

// Round 5
// 261.606 us; speedup vs baseline: 1.2681x; 1.2681x over previous
//
#include <hip/hip_runtime.h>
#include <math.h>

#define CB 512
#define CS 1024
#define CT 50
#define PF 4   // x-prefetch depth / renorm cadence

typedef float v2f __attribute__((ext_vector_type(2)));

__global__ void zero_out_kernel(float* out) { out[0] = 0.0f; }

// Compiler-level fence only — same-wave DS ops complete in order on CDNA.
__device__ __forceinline__ void wave_fence() {
    __builtin_amdgcn_wave_barrier();
    asm volatile("" ::: "memory");
}

__device__ __forceinline__ int lane0_bits(float v) {
    return __builtin_amdgcn_readlane(__float_as_int(v), 0);
}

// quad_perm DPP move (VALU pipe, no DS): ctrl 0xB1 = xor1, 0x4E = xor2
template <int CTRL>
__device__ __forceinline__ float qperm(float v) {
    return __int_as_float(__builtin_amdgcn_update_dpp(
        0, __float_as_int(v), CTRL, 0xf, 0xf, false));
}

__global__ __launch_bounds__(128, 1) void crf_scan_kernel(
    const float* __restrict__ scores,    // (B,S,T)
    const int*   __restrict__ tags,      // (B,S)
    const int*   __restrict__ mask,      // (B,S)
    const float* __restrict__ trans,     // (T,T)
    const float* __restrict__ start_tr,  // (T)
    const float* __restrict__ end_tr,    // (T)
    float* __restrict__ out)             // scalar
{
    const int b    = blockIdx.x;
    const int tid  = threadIdx.x;
    const int w    = tid >> 6;           // wave 0 = forward, wave 1 = backward
    const int lane = tid & 63;
    const int xl   = (lane < CT) ? lane : 0;
    const int g    = lane & 3;           // i-quarter this lane accumulates
    const int m    = lane >> 2;          // quad index; lane owns state == lane
    const bool selb0 = (lane & 1) != 0;
    const bool selb1 = (lane & 2) != 0;

    __shared__ __attribute__((aligned(16))) float sTrans[CT * CT];
    __shared__ __attribute__((aligned(16))) float sP2[2][64];
    __shared__ __attribute__((aligned(16))) float sA[64];
    __shared__ __attribute__((aligned(16))) float sB[64];
    __shared__ float sLZ[2], sN[2];

    for (int k = tid; k < CT * CT; k += 128) sTrans[k] = trans[k];
    __syncthreads();

    // E fragments: lane covers i in [16g, 16g+16), states s = 4m+c, c<4.
    // fwd (w=0): coeff(i,s) = exp(trans[i][s]); bwd (w=1): coeff(i,s) = exp(trans[s][i]).
    // Pads (i>=50 or s>=50) are exactly 0 so pad states stay 0 forever.
    v2f EC0[16], EC1[16];
    {
        const int i0 = 16 * g, s0 = 4 * m;
        #pragma unroll
        for (int k = 0; k < 16; ++k) {
            const int i = i0 + k;
            float e[4] = {0.f, 0.f, 0.f, 0.f};
            if (i < CT) {
                #pragma unroll
                for (int c = 0; c < 4; ++c) {
                    const int s = s0 + c;
                    if (s < CT)
                        e[c] = __expf(w == 0 ? sTrans[i * CT + s]
                                             : sTrans[s * CT + i]);
                }
            }
            EC0[k] = (v2f){e[0], e[1]};
            EC1[k] = (v2f){e[2], e[3]};
        }
    }

    // sequence length (prefix mask)
    const int* mrow = mask + (size_t)b * CS;
    int len = 0;
    for (int t = lane; t < CS; t += 64) len += mrow[t];
    #pragma unroll
    for (int off = 32; off; off >>= 1) len += __shfl_xor(len, off);

    const float* srow = scores + (size_t)b * CS * CT;
    const float* sx   = srow + xl;

    const int tm    = (len - 1) >> 1;
    const int count = (w == 0) ? tm : ((len >= 2) ? (len - 2 - tm) : 0);
    const int base  = (w == 0) ? 1 : (len - 2);
    const int dir   = (w == 0) ? 1 : -1;

    // linear-domain state; pad lanes (state>=50) exactly 0
    float st;
    if (w == 0) {
        st = (lane < CT) ? __expf(start_tr[lane] + sx[0]) : 0.f;
    } else {
        st = (lane < CT)
            ? ((len >= 2) ? __expf(end_tr[lane] + sx[(size_t)(len - 1) * CT])
                          : __expf(end_tr[lane]))
            : 0.f;
    }
    int kexp = 0;
    float* sP = sP2[w];
    const float* sPq = sP + 16 * g;

    // One step: broadcast state via LDS (4 b128 reads), quarter-partial FMAs,
    // quad_perm DPP combine (no DS), select own state, scale by exp(x).
    #define STEP(EX)                                                        \
    {                                                                       \
        sP[lane] = st;                                                      \
        wave_fence();                                                       \
        const float4 p0 = *(const float4*)&sPq[0];                          \
        const float4 p1 = *(const float4*)&sPq[4];                          \
        const float4 p2 = *(const float4*)&sPq[8];                          \
        const float4 p3 = *(const float4*)&sPq[12];                         \
        wave_fence(); /* WAR: reads done before next iteration's write */   \
        float pv[16] = {p0.x,p0.y,p0.z,p0.w, p1.x,p1.y,p1.z,p1.w,           \
                        p2.x,p2.y,p2.z,p2.w, p3.x,p3.y,p3.z,p3.w};          \
        v2f a0 = {0.f,0.f}, a1 = {0.f,0.f};                                 \
        _Pragma("unroll")                                                   \
        for (int kk = 0; kk < 16; ++kk) {                                   \
            const v2f t2 = {pv[kk], pv[kk]};                                \
            a0 = __builtin_elementwise_fma(t2, EC0[kk], a0);                \
            a1 = __builtin_elementwise_fma(t2, EC1[kk], a1);                \
        }                                                                   \
        a0.x += qperm<0xB1>(a0.x); a0.y += qperm<0xB1>(a0.y);               \
        a1.x += qperm<0xB1>(a1.x); a1.y += qperm<0xB1>(a1.y);               \
        a0.x += qperm<0x4E>(a0.x); a0.y += qperm<0x4E>(a0.y);               \
        a1.x += qperm<0x4E>(a1.x); a1.y += qperm<0x4E>(a1.y);               \
        const float o01 = selb0 ? a0.y : a0.x;                              \
        const float o23 = selb0 ? a1.y : a1.x;                              \
        st = (selb1 ? o23 : o01) * (EX);                                    \
    }

    #define RENORM()                                                        \
    {                                                                       \
        int sb = lane0_bits(st);                                            \
        int e  = (sb >> 23) & 0xff;                                         \
        kexp  += e - 127;                                                   \
        st    *= __int_as_float((254 - e) << 23);                           \
    }

    // ---- scan: PF-step chunks, x prefetch, renorm per chunk ----
    float xpf[PF];
    #pragma unroll
    for (int k = 0; k < PF; ++k) {
        int idx = base + dir * k;
        if (idx < 0) idx = 0;
        xpf[k] = sx[(size_t)idx * CT];
    }
    int k = 0;
    while (k + PF <= count) {
        float exk[PF];
        #pragma unroll
        for (int j = 0; j < PF; ++j) exk[j] = __expf(xpf[j]);
        #pragma unroll
        for (int j = 0; j < PF; ++j) {
            int idx = base + dir * (k + PF + j);
            if (idx < 0) idx = 0;
            xpf[j] = sx[(size_t)idx * CT];
        }
        RENORM();
        STEP(exk[0]); STEP(exk[1]); STEP(exk[2]); STEP(exk[3]);
        k += PF;
    }
    for (int r = 0; k < count; ++k, ++r) {
        float e = __expf(xpf[r]);
        RENORM();
        STEP(e);
    }
    // bwd epilogue: B_tm = E * C_{tm+1} (no exp(x) factor)
    if (w == 1 && len >= 2) { RENORM(); STEP(1.0f); }
    RENORM();
    #undef STEP
    #undef RENORM

    // ---- combine across waves ----
    if (w == 0) sA[lane] = (lane < CT) ? st : 0.0f;
    else        sB[lane] = (lane < CT) ? st : 0.0f;
    if (lane == 0) sLZ[w] = (float)kexp * 0.6931471805599453f;
    __syncthreads();

    // numerator: gold-path score, all 128 threads
    const int* trow = tags + (size_t)b * CS;
    float nsum = 0.0f;
    for (int t = tid; t < CS; t += 128) {
        if (t < len) {
            int tg = trow[t];
            nsum += srow[(size_t)t * CT + tg];
            if (t >= 1) nsum += sTrans[trow[t - 1] * CT + tg];
        }
    }
    #pragma unroll
    for (int off = 32; off; off >>= 1) nsum += __shfl_xor(nsum, off);
    if (lane == 0) sN[w] = nsum;

    float den = 0.0f;
    if (w == 0) {
        float vp = sA[lane] * sB[lane];
        #pragma unroll
        for (int off = 32; off; off >>= 1) vp += __shfl_xor(vp, off);
        den = sLZ[0] + sLZ[1] + __logf(vp);
    }
    __syncthreads();

    if (tid == 0) {
        float num = sN[0] + sN[1] + start_tr[trow[0]] + end_tr[trow[len - 1]];
        atomicAdd(out, (den - num) * (1.0f / CB));
    }
}

extern "C" void kernel_launch(void* const* d_in, const int* in_sizes, int n_in,
                              void* d_out, int out_size, void* d_ws, size_t ws_size,
                              hipStream_t stream) {
    const float* scores   = (const float*)d_in[0];
    const int*   tags     = (const int*)d_in[1];
    const int*   mask     = (const int*)d_in[2];
    const float* trans    = (const float*)d_in[3];
    const float* start_tr = (const float*)d_in[4];
    const float* end_tr   = (const float*)d_in[5];
    float* out = (float*)d_out;

    zero_out_kernel<<<1, 1, 0, stream>>>(out);
    crf_scan_kernel<<<CB, 128, 0, stream>>>(scores, tags, mask, trans,
                                            start_tr, end_tr, out);
}